// Round 1
// baseline (365.063 us; speedup 1.0000x reference)
//
#include <hip/hip_runtime.h>

#define N_ROWS   1048576
#define T_COLS   32
#define NBLK     1024
#define BLOCK    256
#define RSTAGE   128
#define STAGES   8            // (N_ROWS/NBLK)/RSTAGE = 1024/128
#define ROWSTR   72           // LDS floats per row: 32 true + 4 pad + 32 pred + 4 pad
#define PRED_OFF 36
#define NWS      2080         // 1024 Gt + 1024 Gp + 32 colsums

__global__ __launch_bounds__(256) void ts_zero(float* __restrict__ ws) {
    for (int i = threadIdx.x; i < NWS; i += 256) ws[i] = 0.0f;
}

__global__ __launch_bounds__(256, 4) void ts_gram(const float* __restrict__ y_pred,
                                                  const float* __restrict__ y_true,
                                                  float* __restrict__ ws) {
    __shared__ __align__(16) float s_data[RSTAGE * ROWSTR];   // 36864 B, reused for reduction

    const int tid = threadIdx.x;
    const int g   = tid >> 5;        // row-group 0..7 (16 rows each per stage)
    const int tau = tid & 31;        // tile task
    const int mtx = tau >> 4;        // 0 = y_true Gram, 1 = y_pred Gram
    const int tt  = tau & 15;
    const int j0  = (tt >> 2) * 8;
    const int k0  = (tt & 3) * 8;
    const int moff = mtx * PRED_OFF;

    float acc[8][8];
    #pragma unroll
    for (int a = 0; a < 8; ++a)
        #pragma unroll
        for (int b = 0; b < 8; ++b) acc[a][b] = 0.0f;
    float sumv[8];
    #pragma unroll
    for (int a = 0; a < 8; ++a) sumv[a] = 0.0f;

    const size_t row0 = (size_t)blockIdx.x * (N_ROWS / NBLK);

    for (int s = 0; s < STAGES; ++s) {
        const float4* gt = (const float4*)(y_true + (row0 + (size_t)s * RSTAGE) * T_COLS);
        const float4* gp = (const float4*)(y_pred + (row0 + (size_t)s * RSTAGE) * T_COLS);
        __syncthreads();   // previous stage's compute done before overwrite
        #pragma unroll
        for (int i = 0; i < 4; ++i) {
            int f  = tid + i * 256;          // 0..1023 float4s per matrix
            int r  = f >> 3;
            int c4 = (f & 7) * 4;
            *(float4*)(s_data + r * ROWSTR + c4)            = gt[f];
            *(float4*)(s_data + r * ROWSTR + PRED_OFF + c4) = gp[f];
        }
        __syncthreads();

        const float* base = s_data + moff;
        #pragma unroll 2
        for (int rr = 0; rr < 16; ++rr) {
            const float* row = base + (g * 16 + rr) * ROWSTR;
            float4 a0 = *(const float4*)(row + j0);
            float4 a1 = *(const float4*)(row + j0 + 4);
            float4 b0 = *(const float4*)(row + k0);
            float4 b1 = *(const float4*)(row + k0 + 4);
            float aj[8] = {a0.x, a0.y, a0.z, a0.w, a1.x, a1.y, a1.z, a1.w};
            float bk[8] = {b0.x, b0.y, b0.z, b0.w, b1.x, b1.y, b1.z, b1.w};
            #pragma unroll
            for (int jj = 0; jj < 8; ++jj)
                #pragma unroll
                for (int kk = 0; kk < 8; ++kk)
                    acc[jj][kk] = fmaf(aj[jj], bk[kk], acc[jj][kk]);
            if (mtx == 0) {
                #pragma unroll
                for (int jj = 0; jj < 8; ++jj) sumv[jj] += aj[jj];
            }
        }
    }

    // ---- block reduction: 8 row-groups share each (tau, jj, kk) entry ----
    __syncthreads();
    for (int i = tid; i < NWS; i += 256) s_data[i] = 0.0f;
    __syncthreads();
    #pragma unroll
    for (int jj = 0; jj < 8; ++jj)
        #pragma unroll
        for (int kk = 0; kk < 8; ++kk)
            atomicAdd(&s_data[mtx * 1024 + (j0 + jj) * 32 + (k0 + kk)], acc[jj][kk]);
    if (mtx == 0 && k0 == 0) {
        #pragma unroll
        for (int jj = 0; jj < 8; ++jj) atomicAdd(&s_data[2048 + j0 + jj], sumv[jj]);
    }
    __syncthreads();
    for (int i = tid; i < NWS; i += 256) atomicAdd(&ws[i], s_data[i]);
}

__global__ __launch_bounds__(1024) void ts_final(const float* __restrict__ w,
                                                 float* __restrict__ out) {
    __shared__ float s_S[32], s_nx[32], s_pn[32];
    __shared__ float s_red[16];
    const int tid = threadIdx.x;
    const float invN = 1.0f / (float)N_ROWS;

    if (tid < 32) {
        float S = w[2048 + tid];
        s_S[tid] = S;
        float d = w[tid * 32 + tid] - S * S * invN;   // centered diag
        s_nx[tid] = sqrtf(d);
        s_pn[tid] = sqrtf(w[1024 + tid * 33]);
    }
    __syncthreads();

    const int j = tid >> 5, k = tid & 31;
    float contrib = 0.0f;
    if (j >= 1 && k > j) {
        float gc  = w[j * 32 + k] - s_S[j] * s_S[k] * invN;
        float pcc = gc / (s_nx[j] * s_nx[k]);
        float cs  = w[1024 + j * 32 + k] / fmaxf(s_pn[j] * s_pn[k], 1e-8f);
        if (pcc >= 0.0f) contrib = 1.0f - cs;
    }
    #pragma unroll
    for (int off = 32; off > 0; off >>= 1) contrib += __shfl_down(contrib, off);
    if ((tid & 63) == 0) s_red[tid >> 6] = contrib;
    __syncthreads();
    if (tid == 0) {
        float tot = 0.0f;
        #pragma unroll
        for (int i = 0; i < 16; ++i) tot += s_red[i];
        out[0] = tot * (1.0f / 465.0f);   // c = (T-1)(T-2)/2
    }
}

extern "C" void kernel_launch(void* const* d_in, const int* in_sizes, int n_in,
                              void* d_out, int out_size, void* d_ws, size_t ws_size,
                              hipStream_t stream) {
    const float* y_pred = (const float*)d_in[0];
    const float* y_true = (const float*)d_in[1];
    float* out = (float*)d_out;
    float* ws  = (float*)d_ws;

    ts_zero<<<1, 256, 0, stream>>>(ws);
    ts_gram<<<NBLK, BLOCK, 0, stream>>>(y_pred, y_true, ws);
    ts_final<<<1, 1024, 0, stream>>>(ws, out);
}